// Round 8
// baseline (344.392 us; speedup 1.0000x reference)
//
#include <hip/hip_runtime.h>
#include <hip/hip_bf16.h>

#define NN 6144
#define INPUT 1024
#define HID 256

using frag  = __attribute__((ext_vector_type(8))) short;   // 8 bf16
using f32x4 = __attribute__((ext_vector_type(4))) float;

union FU { frag f; unsigned u[4]; };

static __device__ __forceinline__ unsigned short bf16u(float x) {
    unsigned u = __float_as_uint(x);
    u += 0x7fff + ((u >> 16) & 1);     // RNE
    return (unsigned short)(u >> 16);
}

// pack 2 f32 -> 2 bf16 (RNE) in one inst — no builtin on gfx950
static __device__ __forceinline__ unsigned cvtpk(float lo, float hi) {
    unsigned r;
    asm("v_cvt_pk_bf16_f32 %0, %1, %2" : "=v"(r) : "v"(lo), "v"(hi));
    return r;
}

// ============ FRAG-ORDER TILE LAYOUT (unchanged from r7) ============
// 16x32 bf16 tile as 1 KB: slot l = MFMA lane l's fragment (row l&15, k (l>>4)*8..+7)

// ---------------- prep: X -> Xbp (frag tiles), W -> Wtp (frag tiles) ----------------
__global__ __launch_bounds__(256) void k_prep(const float* __restrict__ X,
                                              const float* __restrict__ W,
                                              unsigned short* __restrict__ Xbp,
                                              unsigned short* __restrict__ Wtp) {
    int b = blockIdx.x;
    if (b < 3072) {                         // X: 6144 x 1024, thread -> (i, k8)
        int t = b * 256 + threadIdx.x;
        int i = t >> 7, k8 = t & 127;
        const float4* p = reinterpret_cast<const float4*>(X + (size_t)i * INPUT + k8 * 8);
        float4 x0 = p[0], x1 = p[1];
        frag v;
        v[0] = (short)bf16u(x0.x); v[1] = (short)bf16u(x0.y);
        v[2] = (short)bf16u(x0.z); v[3] = (short)bf16u(x0.w);
        v[4] = (short)bf16u(x1.x); v[5] = (short)bf16u(x1.y);
        v[6] = (short)bf16u(x1.z); v[7] = (short)bf16u(x1.w);
        size_t off = ((size_t)((i >> 4) * 32 + (k8 >> 2))) * 512 + (k8 & 3) * 128 + (i & 15) * 8;
        *reinterpret_cast<frag*>(Xbp + off) = v;
    } else {                                // W: 1024 x 256, thread -> (n, k8)
        int u = (b - 3072) * 256 + threadIdx.x;
        int n = u >> 7, k8 = u & 127;
        int k = k8 * 8;
        frag v;
#pragma unroll
        for (int e = 0; e < 8; e++) v[e] = (short)bf16u(W[(size_t)(k + e) * HID + n]);
        size_t off = ((size_t)((n >> 4) * 32 + (k8 >> 2))) * 512 + (k8 & 3) * 128 + (n & 15) * 8;
        *reinterpret_cast<frag*>(Wtp + off) = v;
    }
}

// ---------------- GEMM1 (unchanged r7: ~17 us by ledger): hTp frag-order + s1/s2 ----------------
__global__ __launch_bounds__(256, 4) void k_gemm1(const unsigned short* __restrict__ Xbp,
                                                  const unsigned short* __restrict__ Wtp,
                                                  const float* __restrict__ a_edge,
                                                  unsigned short* __restrict__ hTp,
                                                  float* __restrict__ s1,
                                                  float* __restrict__ s2) {
    int t = threadIdx.x;
    int w = t >> 6, l = t & 63, lm = l & 15, q = l >> 4;
    int bx = blockIdx.x, by = blockIdx.y;
    int i0 = bx * 32;
    int tn = by * 4 + w;

    const unsigned short* pA0 = Xbp + (size_t)(bx * 2) * 32 * 512 + l * 8;
    const unsigned short* pA1 = Xbp + (size_t)(bx * 2 + 1) * 32 * 512 + l * 8;
    const unsigned short* pB  = Wtp + (size_t)tn * 32 * 512 + l * 8;

    f32x4 acc0 = {}, acc1 = {};
    frag a0s[3], a1s[3], bs[3];
#pragma unroll
    for (int s = 0; s < 2; s++) {
        a0s[s] = *reinterpret_cast<const frag*>(pA0 + s * 512);
        a1s[s] = *reinterpret_cast<const frag*>(pA1 + s * 512);
        bs[s]  = *reinterpret_cast<const frag*>(pB  + s * 512);
    }
#pragma unroll
    for (int tk = 0; tk < 32; tk++) {
        int cur = tk % 3;
        if (tk < 30) {
            int nx = (tk + 2) % 3;
            a0s[nx] = *reinterpret_cast<const frag*>(pA0 + (tk + 2) * 512);
            a1s[nx] = *reinterpret_cast<const frag*>(pA1 + (tk + 2) * 512);
            bs[nx]  = *reinterpret_cast<const frag*>(pB  + (tk + 2) * 512);
        }
        acc0 = __builtin_amdgcn_mfma_f32_16x16x32_bf16(a0s[cur], bs[cur], acc0, 0, 0, 0);
        acc1 = __builtin_amdgcn_mfma_f32_16x16x32_bf16(a1s[cur], bs[cur], acc1, 0, 0, 0);
    }

    unsigned short* tb = hTp + ((size_t)bx * 16 + tn) * 512;
    ushort4 o;
    o.x = bf16u(acc0[0]); o.y = bf16u(acc0[1]); o.z = bf16u(acc0[2]); o.w = bf16u(acc0[3]);
    *reinterpret_cast<ushort4*>(tb + (q >> 1) * 128 + lm * 8 + (q & 1) * 4) = o;
    o.x = bf16u(acc1[0]); o.y = bf16u(acc1[1]); o.z = bf16u(acc1[2]); o.w = bf16u(acc1[3]);
    *reinterpret_cast<ushort4*>(tb + (2 + (q >> 1)) * 128 + lm * 8 + (q & 1) * 4) = o;

    float a1v = a_edge[tn * 16 + lm], a2v = a_edge[HID + tn * 16 + lm];
#pragma unroll
    for (int h = 0; h < 2; h++) {
        const f32x4& ac = h ? acc1 : acc0;
#pragma unroll
        for (int r = 0; r < 4; r++) {
            float v1 = ac[r] * a1v, v2 = ac[r] * a2v;
            v1 += __shfl_xor(v1, 1); v2 += __shfl_xor(v2, 1);
            v1 += __shfl_xor(v1, 2); v2 += __shfl_xor(v2, 2);
            v1 += __shfl_xor(v1, 4); v2 += __shfl_xor(v2, 4);
            v1 += __shfl_xor(v1, 8); v2 += __shfl_xor(v2, 8);
            if (lm == 0) {
                atomicAdd(&s1[i0 + h * 16 + q * 4 + r], v1);
                atomicAdd(&s2[i0 + h * 16 + q * 4 + r], v2);
            }
        }
    }
}

// ---------------- fused attention: SWAPPED OPERANDS, no LDS, no barriers ----------------
// grid (192,4); block 256 = 4 independent waves. Compute U^T = hTp(A) x P(B):
// B-frag lane l needs exactly P[i=l&15][j=js+(l>>4)*8+e] -- computed IN-LANE from
// that lane's own adj/s2 loads (no P staging, no cross-lane). Wave: n-slice 64
// (4 A-tiles, dense 1KB loads), i-block 32 (2 B-frags/step), 48 j-steps of 32.
// Deletes: P LDS round-trip, adjS, both barriers, all lockstep -> waves slip freely.
// Costs accepted: adj read 4x/block (16-line row-gathers), exp 4x redundant (VALU,
// hidden under TA). D-tile output stored in native frag order (dense); k_norm unpermutes.
__global__ __launch_bounds__(256, 3) void k_attn(const int* __restrict__ adj,
                                                 const float* __restrict__ s1,
                                                 const float* __restrict__ s2,
                                                 const unsigned short* __restrict__ hTp,
                                                 float* __restrict__ U4p,
                                                 float* __restrict__ denom4) {
    int t = threadIdx.x;
    int w = t >> 6, l = t & 63, lm = l & 15, q = l >> 4;
    int bx = blockIdx.x, i0 = bx * 32;
    int q4 = blockIdx.y, j0 = q4 * 1536;

    float s1a = s1[i0 + lm], s1b = s1[i0 + 16 + lm];
    const int*   aL = adj + (size_t)(i0 + lm) * NN + j0 + q * 8;
    const int*   aH = aL + (size_t)16 * NN;
    const float* sp = s2 + j0 + q * 8;
    // A-tiles: (tj = q4*48 + step, tn = w*4 + a); lane-direct frag slots
    const unsigned short* Ab = hTp + ((size_t)(q4 * 48) * 16 + w * 4) * 512 + l * 8;

    f32x4 accL[4] = {}, accH[4] = {};
    float dsL = 0.f, dsH = 0.f;

#pragma unroll 2
    for (int st = 0; st < 48; st++) {
        // ---- A: 4 dense 1KB tile loads ----
        const unsigned short* Abs = Ab + (size_t)st * 16 * 512;
        frag A0 = *reinterpret_cast<const frag*>(Abs);
        frag A1 = *reinterpret_cast<const frag*>(Abs + 512);
        frag A2 = *reinterpret_cast<const frag*>(Abs + 1024);
        frag A3 = *reinterpret_cast<const frag*>(Abs + 1536);
        // ---- per-lane adj + s2 (this lane's 8 j's for both i-halves) ----
        int4   al0 = *reinterpret_cast<const int4*>(aL + st * 32);
        int4   al1 = *reinterpret_cast<const int4*>(aL + st * 32 + 4);
        int4   ah0 = *reinterpret_cast<const int4*>(aH + st * 32);
        int4   ah1 = *reinterpret_cast<const int4*>(aH + st * 32 + 4);
        float4 sv0 = *reinterpret_cast<const float4*>(sp + st * 32);
        float4 sv1 = *reinterpret_cast<const float4*>(sp + st * 32 + 4);

        // ---- build B0 (rows i0..i0+15) ----
        float sc, wv, p0, p1, p2, p3, p4, p5, p6, p7;
        FU b0, b1;
        sc = s1a + sv0.x; wv = fmaxf(sc, 0.2f * sc); p0 = al0.x ? __expf(wv) : 0.f;
        sc = s1a + sv0.y; wv = fmaxf(sc, 0.2f * sc); p1 = al0.y ? __expf(wv) : 0.f;
        sc = s1a + sv0.z; wv = fmaxf(sc, 0.2f * sc); p2 = al0.z ? __expf(wv) : 0.f;
        sc = s1a + sv0.w; wv = fmaxf(sc, 0.2f * sc); p3 = al0.w ? __expf(wv) : 0.f;
        sc = s1a + sv1.x; wv = fmaxf(sc, 0.2f * sc); p4 = al1.x ? __expf(wv) : 0.f;
        sc = s1a + sv1.y; wv = fmaxf(sc, 0.2f * sc); p5 = al1.y ? __expf(wv) : 0.f;
        sc = s1a + sv1.z; wv = fmaxf(sc, 0.2f * sc); p6 = al1.z ? __expf(wv) : 0.f;
        sc = s1a + sv1.w; wv = fmaxf(sc, 0.2f * sc); p7 = al1.w ? __expf(wv) : 0.f;
        dsL += ((p0 + p1) + (p2 + p3)) + ((p4 + p5) + (p6 + p7));
        b0.u[0] = cvtpk(p0, p1); b0.u[1] = cvtpk(p2, p3);
        b0.u[2] = cvtpk(p4, p5); b0.u[3] = cvtpk(p6, p7);
        // ---- build B1 (rows i0+16..i0+31) ----
        sc = s1b + sv0.x; wv = fmaxf(sc, 0.2f * sc); p0 = ah0.x ? __expf(wv) : 0.f;
        sc = s1b + sv0.y; wv = fmaxf(sc, 0.2f * sc); p1 = ah0.y ? __expf(wv) : 0.f;
        sc = s1b + sv0.z; wv = fmaxf(sc, 0.2f * sc); p2 = ah0.z ? __expf(wv) : 0.f;
        sc = s1b + sv0.w; wv = fmaxf(sc, 0.2f * sc); p3 = ah0.w ? __expf(wv) : 0.f;
        sc = s1b + sv1.x; wv = fmaxf(sc, 0.2f * sc); p4 = ah1.x ? __expf(wv) : 0.f;
        sc = s1b + sv1.y; wv = fmaxf(sc, 0.2f * sc); p5 = ah1.y ? __expf(wv) : 0.f;
        sc = s1b + sv1.z; wv = fmaxf(sc, 0.2f * sc); p6 = ah1.z ? __expf(wv) : 0.f;
        sc = s1b + sv1.w; wv = fmaxf(sc, 0.2f * sc); p7 = ah1.w ? __expf(wv) : 0.f;
        dsH += ((p0 + p1) + (p2 + p3)) + ((p4 + p5) + (p6 + p7));
        b1.u[0] = cvtpk(p0, p1); b1.u[1] = cvtpk(p2, p3);
        b1.u[2] = cvtpk(p4, p5); b1.u[3] = cvtpk(p6, p7);

        // ---- 8 MFMA: D[n][i] += hT[n][j] * P[i][j] ----
        __builtin_amdgcn_s_setprio(1);
        accL[0] = __builtin_amdgcn_mfma_f32_16x16x32_bf16(A0, b0.f, accL[0], 0, 0, 0);
        accH[0] = __builtin_amdgcn_mfma_f32_16x16x32_bf16(A0, b1.f, accH[0], 0, 0, 0);
        accL[1] = __builtin_amdgcn_mfma_f32_16x16x32_bf16(A1, b0.f, accL[1], 0, 0, 0);
        accH[1] = __builtin_amdgcn_mfma_f32_16x16x32_bf16(A1, b1.f, accH[1], 0, 0, 0);
        accL[2] = __builtin_amdgcn_mfma_f32_16x16x32_bf16(A2, b0.f, accL[2], 0, 0, 0);
        accH[2] = __builtin_amdgcn_mfma_f32_16x16x32_bf16(A2, b1.f, accH[2], 0, 0, 0);
        accL[3] = __builtin_amdgcn_mfma_f32_16x16x32_bf16(A3, b0.f, accL[3], 0, 0, 0);
        accH[3] = __builtin_amdgcn_mfma_f32_16x16x32_bf16(A3, b1.f, accH[3], 0, 0, 0);
        __builtin_amdgcn_s_setprio(0);
    }

    // denominator: lane (lm,q) holds rows lm / 16+lm over q-interleaved j; reduce over q.
    // All 4 waves computed identical sums (redundant) -> wave 0 writes.
    dsL += __shfl_xor(dsL, 16); dsL += __shfl_xor(dsL, 32);
    dsH += __shfl_xor(dsH, 16); dsH += __shfl_xor(dsH, 32);
    if (w == 0 && l < 16) {
        denom4[(size_t)q4 * NN + i0 + l]      = dsL;
        denom4[(size_t)q4 * NN + i0 + 16 + l] = dsH;
    }

    // U partials in native D-tile order: tile (q4, bx, tn) of [2 halves][n_sub 16][i_sub 16]
    float* Ub = U4p + (((size_t)q4 * 192 + bx) * 16) * 512;
#pragma unroll
    for (int a = 0; a < 4; a++) {
        float* tb = Ub + (size_t)(w * 4 + a) * 512;
#pragma unroll
        for (int r = 0; r < 4; r++) {
            tb[(q * 4 + r) * 16 + lm]       = accL[a][r];   // h=0
            tb[256 + (q * 4 + r) * 16 + lm] = accH[a][r];   // h=1
        }
    }
}

// ---------------- normalize + un-permute: out = (sum_q U4p) / (sum_q denom4) ----------------
// grid 192 (i-blocks of 32); block 256. Dense reads of U4p, LDS transpose, dense writes.
__global__ __launch_bounds__(256) void k_norm(const float* __restrict__ U4p,
                                              const float* __restrict__ denom4,
                                              float* __restrict__ out) {
    __shared__ float T[32][257];
    int bx = blockIdx.x, t = threadIdx.x;
    const float* base = U4p + (size_t)bx * 16 * 512;
    const size_t QS = (size_t)192 * 16 * 512;
#pragma unroll
    for (int e = 0; e < 32; e++) {
        int f = e * 256 + t;                    // 0..8191 over (tn, h, n_sub, i_sub)
        size_t off = (size_t)(f >> 9) * 512 + (f & 511);
        float u = base[off] + base[QS + off] + base[2 * QS + off] + base[3 * QS + off];
        int tn = f >> 9, h = (f >> 8) & 1, ns = (f >> 4) & 15, is = f & 15;
        T[h * 16 + is][tn * 16 + ns] = u;
    }
    __syncthreads();
    int r = t >> 3, c0 = (t & 7) * 32;
    int i = bx * 32 + r;
    float d = denom4[i] + denom4[NN + i] + denom4[2 * NN + i] + denom4[3 * NN + i];
    float inv = (d != 0.f) ? 1.f / d : 0.f;
#pragma unroll
    for (int c = c0; c < c0 + 32; c += 4) {
        float4 v;
        v.x = T[r][c] * inv; v.y = T[r][c + 1] * inv;
        v.z = T[r][c + 2] * inv; v.w = T[r][c + 3] * inv;
        *reinterpret_cast<float4*>(&out[(size_t)i * HID + c]) = v;
    }
}

extern "C" void kernel_launch(void* const* d_in, const int* in_sizes, int n_in,
                              void* d_out, int out_size, void* d_ws, size_t ws_size,
                              hipStream_t stream) {
    const float* X      = (const float*)d_in[0];   // 6144x1024
    const float* W      = (const float*)d_in[1];   // 1024x256
    const float* a_edge = (const float*)d_in[2];   // 512
    const int*   adj    = (const int*)d_in[3];     // 6144x6144
    float* out = (float*)d_out;

    float* U4p    = (float*)d_ws;                          // 4*192*16*512 f32 (25.2 MB)
    float* denom4 = U4p + (size_t)4 * NN * HID;            // 4*NN
    float* s1     = denom4 + (size_t)4 * NN;               // NN
    float* s2     = s1 + NN;                               // NN
    unsigned short* hTp = (unsigned short*)(s2 + NN);      // 192*16 frag tiles (3.1 MB)
    unsigned short* Wtp = hTp + (size_t)HID * NN;          // 16*32 frag tiles (0.5 MB)
    // Xbp (12.6 MB) ALIASES U4p: dead before k_attn fully overwrites U4p.
    unsigned short* Xbp = (unsigned short*)U4p;

    hipMemsetAsync(s1, 0, 2 * NN * sizeof(float), stream);
    k_prep<<<3072 + 128, 256, 0, stream>>>(X, W, Xbp, Wtp);
    k_gemm1<<<dim3(NN / 32, 4), 256, 0, stream>>>(Xbp, Wtp, a_edge, hTp, s1, s2);
    k_attn<<<dim3(NN / 32, 4), 256, 0, stream>>>(adj, s1, s2, hTp, U4p, denom4);
    k_norm<<<NN / 32, 256, 0, stream>>>(U4p, denom4, out);
}

// Round 9
// 296.927 us; speedup vs baseline: 1.1599x; 1.1599x over previous
//
#include <hip/hip_runtime.h>
#include <hip/hip_bf16.h>

#define NN 6144
#define INPUT 1024
#define HID 256

using frag  = __attribute__((ext_vector_type(8))) short;   // 8 bf16
using f32x4 = __attribute__((ext_vector_type(4))) float;

static __device__ __forceinline__ unsigned short bf16u(float x) {
    unsigned u = __float_as_uint(x);
    u += 0x7fff + ((u >> 16) & 1);     // RNE
    return (unsigned short)(u >> 16);
}

// async global->LDS, NT cache policy (aux=2): adj streams ~19MB/XCD through the
// 4MB L2 per dispatch; NT keeps it from evicting the L2-resident hTp that every
// block re-reads. No VGPR dest: allocator cannot sink it; gated by counted vmcnt.
static __device__ __forceinline__ void gll16nt(const void* g, void* l) {
    __builtin_amdgcn_global_load_lds((__attribute__((address_space(1))) const void*)g,
                                     (__attribute__((address_space(3))) void*)l, 16, 0, 2);
}

// LDS-producer barrier without the __syncthreads vmcnt(0) drain.
static __device__ __forceinline__ void lds_barrier() {
    asm volatile("s_waitcnt lgkmcnt(0)" ::: "memory");
    __builtin_amdgcn_s_barrier();
    __builtin_amdgcn_sched_barrier(0);
}

// ============ FRAG-ORDER TILE LAYOUT (r7) ============
// 16x32 bf16 tile as 1 KB: slot l = MFMA lane l's fragment (row l&15, k (l>>4)*8..+7)

// ---------------- prep: X -> Xbp (frag tiles), W -> Wtp (frag tiles) ----------------
__global__ __launch_bounds__(256) void k_prep(const float* __restrict__ X,
                                              const float* __restrict__ W,
                                              unsigned short* __restrict__ Xbp,
                                              unsigned short* __restrict__ Wtp) {
    int b = blockIdx.x;
    if (b < 3072) {                         // X: 6144 x 1024, thread -> (i, k8)
        int t = b * 256 + threadIdx.x;
        int i = t >> 7, k8 = t & 127;
        const float4* p = reinterpret_cast<const float4*>(X + (size_t)i * INPUT + k8 * 8);
        float4 x0 = p[0], x1 = p[1];
        frag v;
        v[0] = (short)bf16u(x0.x); v[1] = (short)bf16u(x0.y);
        v[2] = (short)bf16u(x0.z); v[3] = (short)bf16u(x0.w);
        v[4] = (short)bf16u(x1.x); v[5] = (short)bf16u(x1.y);
        v[6] = (short)bf16u(x1.z); v[7] = (short)bf16u(x1.w);
        size_t off = ((size_t)((i >> 4) * 32 + (k8 >> 2))) * 512 + (k8 & 3) * 128 + (i & 15) * 8;
        *reinterpret_cast<frag*>(Xbp + off) = v;
    } else {                                // W: 1024 x 256, thread -> (n, k8)
        int u = (b - 3072) * 256 + threadIdx.x;
        int n = u >> 7, k8 = u & 127;
        int k = k8 * 8;
        frag v;
#pragma unroll
        for (int e = 0; e < 8; e++) v[e] = (short)bf16u(W[(size_t)(k + e) * HID + n]);
        size_t off = ((size_t)((n >> 4) * 32 + (k8 >> 2))) * 512 + (k8 & 3) * 128 + (n & 15) * 8;
        *reinterpret_cast<frag*>(Wtp + off) = v;
    }
}

// ---------------- GEMM1 (unchanged r7): hTp frag-order + s1/s2 ----------------
__global__ __launch_bounds__(256, 4) void k_gemm1(const unsigned short* __restrict__ Xbp,
                                                  const unsigned short* __restrict__ Wtp,
                                                  const float* __restrict__ a_edge,
                                                  unsigned short* __restrict__ hTp,
                                                  float* __restrict__ s1,
                                                  float* __restrict__ s2) {
    int t = threadIdx.x;
    int w = t >> 6, l = t & 63, lm = l & 15, q = l >> 4;
    int bx = blockIdx.x, by = blockIdx.y;
    int i0 = bx * 32;
    int tn = by * 4 + w;

    const unsigned short* pA0 = Xbp + (size_t)(bx * 2) * 32 * 512 + l * 8;
    const unsigned short* pA1 = Xbp + (size_t)(bx * 2 + 1) * 32 * 512 + l * 8;
    const unsigned short* pB  = Wtp + (size_t)tn * 32 * 512 + l * 8;

    f32x4 acc0 = {}, acc1 = {};
    frag a0s[3], a1s[3], bs[3];
#pragma unroll
    for (int s = 0; s < 2; s++) {
        a0s[s] = *reinterpret_cast<const frag*>(pA0 + s * 512);
        a1s[s] = *reinterpret_cast<const frag*>(pA1 + s * 512);
        bs[s]  = *reinterpret_cast<const frag*>(pB  + s * 512);
    }
#pragma unroll
    for (int tk = 0; tk < 32; tk++) {
        int cur = tk % 3;
        if (tk < 30) {
            int nx = (tk + 2) % 3;
            a0s[nx] = *reinterpret_cast<const frag*>(pA0 + (tk + 2) * 512);
            a1s[nx] = *reinterpret_cast<const frag*>(pA1 + (tk + 2) * 512);
            bs[nx]  = *reinterpret_cast<const frag*>(pB  + (tk + 2) * 512);
        }
        acc0 = __builtin_amdgcn_mfma_f32_16x16x32_bf16(a0s[cur], bs[cur], acc0, 0, 0, 0);
        acc1 = __builtin_amdgcn_mfma_f32_16x16x32_bf16(a1s[cur], bs[cur], acc1, 0, 0, 0);
    }

    unsigned short* tb = hTp + ((size_t)bx * 16 + tn) * 512;
    ushort4 o;
    o.x = bf16u(acc0[0]); o.y = bf16u(acc0[1]); o.z = bf16u(acc0[2]); o.w = bf16u(acc0[3]);
    *reinterpret_cast<ushort4*>(tb + (q >> 1) * 128 + lm * 8 + (q & 1) * 4) = o;
    o.x = bf16u(acc1[0]); o.y = bf16u(acc1[1]); o.z = bf16u(acc1[2]); o.w = bf16u(acc1[3]);
    *reinterpret_cast<ushort4*>(tb + (2 + (q >> 1)) * 128 + lm * 8 + (q & 1) * 4) = o;

    float a1v = a_edge[tn * 16 + lm], a2v = a_edge[HID + tn * 16 + lm];
#pragma unroll
    for (int h = 0; h < 2; h++) {
        const f32x4& ac = h ? acc1 : acc0;
#pragma unroll
        for (int r = 0; r < 4; r++) {
            float v1 = ac[r] * a1v, v2 = ac[r] * a2v;
            v1 += __shfl_xor(v1, 1); v2 += __shfl_xor(v2, 1);
            v1 += __shfl_xor(v1, 2); v2 += __shfl_xor(v2, 2);
            v1 += __shfl_xor(v1, 4); v2 += __shfl_xor(v2, 4);
            v1 += __shfl_xor(v1, 8); v2 += __shfl_xor(v2, 8);
            if (lm == 0) {
                atomicAdd(&s1[i0 + h * 16 + q * 4 + r], v1);
                atomicAdd(&s2[i0 + h * 16 + q * 4 + r], v2);
            }
        }
    }
}

// ---------------- fused attention: r7 skeleton, SINGLE barrier per chunk ----------------
// grid (192,4); block 512 = 8 waves. Key fix over r7: adjS staging is WAVE-PRIVATE
// (wave w glls rows 4w..4w+3; the builder threads for those rows ARE wave w), so the
// block-wide staging barrier was never needed -- only s2S made it cross-wave, and s2
// is now loaded per-builder-lane (L1-hot). Per chunk: {s2[2] -> bf[8] -> gll(c+1)[2]
// -> asm vmcnt(12) retires exactly gll(c) -> build P (wave-local) -> lds_barrier ->
// MFMA (compiler vmcnt(2) for bf, gll(c+1) stays in flight)}. 12 barriers vs r7's 24;
// build/MFMA phases decouple across waves. adj staged NT to preserve hTp L2 residency.
__global__ __launch_bounds__(512, 2) void k_attn(const int* __restrict__ adj,
                                                 const float* __restrict__ s1,
                                                 const float* __restrict__ s2,
                                                 const unsigned short* __restrict__ hTp,
                                                 float* __restrict__ U4,
                                                 float* __restrict__ denom4) {
    __shared__ unsigned short P[2][32][136];   // 17408 B
    __shared__ int adjS[2][32][128];           // 32768 B, linear (gll dest), wave-private rows
    int t = threadIdx.x;
    int m = t >> 4, cg = t & 15;               // builder: row m (0..31), col-group cg
    int i0 = blockIdx.x * 32;
    int q4 = blockIdx.y, j0 = q4 * 1536;
    int w = t >> 6, l = t & 63, lm = l & 15, q = l >> 4;

    float s1v = s1[i0 + m];
    // staging: wave w stages adj rows 4w..4w+3 (2 gll16 x 2 rows each)
    const int* astage = adj + (size_t)(i0 + w * 4 + (l >> 5)) * NN + j0 + (l & 31) * 4;
    const float* s2p = s2 + j0 + cg * 8;       // builder-lane direct (L1-hot)

    // dense B-frag base: tile (tj, tn = w*2+nt) at (tj*16+tn)*512 + l*8 ushorts
    const unsigned short* hb = hTp + (size_t)(w * 2) * 512 + l * 8;
    int tjb = q4 * 48;

    f32x4 acc[2][2] = {};
    float dsum = 0.f;

    // prologue: stage chunk 0 into adjS[0]
    gll16nt(astage, &adjS[0][w * 4][0]);
    gll16nt(astage + 2 * NN, &adjS[0][w * 4 + 2][0]);

    for (int c = 0; c < 12; c++) {
        int buf = c & 1, jc = c * 128;

        // ---- issue order (counted): s2[2], bf[8], gll(c+1)[2] ----
        float4 sv0 = *reinterpret_cast<const float4*>(s2p + jc);
        float4 sv1 = *reinterpret_cast<const float4*>(s2p + jc + 4);

        frag bf[8];
#pragma unroll
        for (int kk = 0; kk < 4; kk++)
#pragma unroll
            for (int nt = 0; nt < 2; nt++)
                bf[kk * 2 + nt] = *reinterpret_cast<const frag*>(
                    hb + ((size_t)(tjb + c * 4 + kk) * 16 + nt) * 512);

        // next chunk (c=11: dummy re-stage of same chunk into dead buffer keeps the
        // outstanding-count uniform; never read)
        int jn = (c < 11) ? jc + 128 : jc;
        gll16nt(astage + jn, &adjS[buf ^ 1][w * 4][0]);
        gll16nt(astage + jn + 2 * NN, &adjS[buf ^ 1][w * 4 + 2][0]);

        // outstanding: gll(c)[2, oldest] + s2[2] + bf[8] + gll(c+1)[2] = 14
        // -> vmcnt(12) retires exactly gll(c). Wave-private: no barrier needed.
        asm volatile("s_waitcnt vmcnt(12)" ::: "memory");
        __builtin_amdgcn_sched_barrier(0);

        // ---- build P[buf] rows 4w..4w+3 from wave-private adjS (VALU only) ----
        {
            const int* aL = &adjS[buf][m][cg * 8];
            int4 av0 = *reinterpret_cast<const int4*>(aL);
            int4 av1 = *reinterpret_cast<const int4*>(aL + 4);
            float sc, wv, p0, p1, p2, p3, p4, p5, p6, p7;
            sc = s1v + sv0.x; wv = fmaxf(sc, 0.2f * sc); p0 = av0.x ? __expf(wv) : 0.f;
            sc = s1v + sv0.y; wv = fmaxf(sc, 0.2f * sc); p1 = av0.y ? __expf(wv) : 0.f;
            sc = s1v + sv0.z; wv = fmaxf(sc, 0.2f * sc); p2 = av0.z ? __expf(wv) : 0.f;
            sc = s1v + sv0.w; wv = fmaxf(sc, 0.2f * sc); p3 = av0.w ? __expf(wv) : 0.f;
            sc = s1v + sv1.x; wv = fmaxf(sc, 0.2f * sc); p4 = av1.x ? __expf(wv) : 0.f;
            sc = s1v + sv1.y; wv = fmaxf(sc, 0.2f * sc); p5 = av1.y ? __expf(wv) : 0.f;
            sc = s1v + sv1.z; wv = fmaxf(sc, 0.2f * sc); p6 = av1.z ? __expf(wv) : 0.f;
            sc = s1v + sv1.w; wv = fmaxf(sc, 0.2f * sc); p7 = av1.w ? __expf(wv) : 0.f;
            dsum += ((p0 + p1) + (p2 + p3)) + ((p4 + p5) + (p6 + p7));
            frag pk;
            pk[0] = (short)bf16u(p0); pk[1] = (short)bf16u(p1);
            pk[2] = (short)bf16u(p2); pk[3] = (short)bf16u(p3);
            pk[4] = (short)bf16u(p4); pk[5] = (short)bf16u(p5);
            pk[6] = (short)bf16u(p6); pk[7] = (short)bf16u(p7);
            *reinterpret_cast<frag*>(&P[buf][m][cg * 8]) = pk;
        }

        // single barrier per chunk: P[buf] visible block-wide; P[buf^1]'s readers
        // (prev chunk's MFMA) all passed their own prior barrier before overwrite.
        lds_barrier();

        // ---- consume: 4 k-steps x (2 A-halves x 2 B-frags) = 16 MFMA/wave ----
        __builtin_amdgcn_s_setprio(1);
#pragma unroll
        for (int kk = 0; kk < 4; kk++) {
            frag a0 = *reinterpret_cast<const frag*>(&P[buf][lm][kk * 32 + q * 8]);
            frag a1 = *reinterpret_cast<const frag*>(&P[buf][16 + lm][kk * 32 + q * 8]);
#pragma unroll
            for (int nt = 0; nt < 2; nt++) {
                acc[0][nt] = __builtin_amdgcn_mfma_f32_16x16x32_bf16(a0, bf[kk * 2 + nt], acc[0][nt], 0, 0, 0);
                acc[1][nt] = __builtin_amdgcn_mfma_f32_16x16x32_bf16(a1, bf[kk * 2 + nt], acc[1][nt], 0, 0, 0);
            }
        }
        __builtin_amdgcn_s_setprio(0);
    }

    // denom partial: lanes with same m are cg=0..15 -> reduce over cg
    float v = dsum;
    v += __shfl_xor(v, 1); v += __shfl_xor(v, 2);
    v += __shfl_xor(v, 4); v += __shfl_xor(v, 8);
    if (cg == 0) denom4[(size_t)q4 * NN + i0 + m] = v;

    // U4 partial: plain stores (64B-dense per 16-lane group)
    float* Ub = U4 + (size_t)q4 * NN * HID;
#pragma unroll
    for (int h = 0; h < 2; h++)
#pragma unroll
        for (int nt = 0; nt < 2; nt++)
#pragma unroll
            for (int r = 0; r < 4; r++)
                Ub[(size_t)(i0 + h * 16 + q * 4 + r) * HID + w * 32 + nt * 16 + lm] = acc[h][nt][r];
}

// ---------------- normalize: out = (sum_q U4) / (sum_q denom4) ----------------
__global__ __launch_bounds__(256) void k_norm(const float* __restrict__ U4,
                                              const float* __restrict__ denom4,
                                              float* __restrict__ out) {
    int i = blockIdx.x, t = threadIdx.x;
    size_t S = (size_t)NN * HID;
    size_t base = (size_t)i * HID + t;
    float u = U4[base] + U4[base + S] + U4[base + 2 * S] + U4[base + 3 * S];
    float d = denom4[i] + denom4[i + NN] + denom4[i + 2 * NN] + denom4[i + 3 * NN];
    out[base] = (d != 0.f) ? u / d : 0.f;
}

extern "C" void kernel_launch(void* const* d_in, const int* in_sizes, int n_in,
                              void* d_out, int out_size, void* d_ws, size_t ws_size,
                              hipStream_t stream) {
    const float* X      = (const float*)d_in[0];   // 6144x1024
    const float* W      = (const float*)d_in[1];   // 1024x256
    const float* a_edge = (const float*)d_in[2];   // 512
    const int*   adj    = (const int*)d_in[3];     // 6144x6144
    float* out = (float*)d_out;

    float* U4     = (float*)d_ws;                          // 4*NN*HID f32 (25.2 MB)
    float* denom4 = U4 + (size_t)4 * NN * HID;             // 4*NN
    float* s1     = denom4 + (size_t)4 * NN;               // NN
    float* s2     = s1 + NN;                               // NN
    unsigned short* hTp = (unsigned short*)(s2 + NN);      // frag tiles (3.1 MB)
    unsigned short* Wtp = hTp + (size_t)HID * NN;          // frag tiles (0.5 MB)
    // Xbp (12.6 MB) ALIASES U4: dead before k_attn fully overwrites U4.
    unsigned short* Xbp = (unsigned short*)U4;

    hipMemsetAsync(s1, 0, 2 * NN * sizeof(float), stream);
    k_prep<<<3072 + 128, 256, 0, stream>>>(X, W, Xbp, Wtp);
    k_gemm1<<<dim3(NN / 32, 4), 256, 0, stream>>>(Xbp, Wtp, a_edge, hTp, s1, s2);
    k_attn<<<dim3(NN / 32, 4), 512, 0, stream>>>(adj, s1, s2, hTp, U4, denom4);
    k_norm<<<NN, 256, 0, stream>>>(U4, denom4, out);
}